// Round 6
// baseline (24076.378 us; speedup 1.0000x reference)
//
#include <hip/hip_runtime.h>
#include <math.h>

// LSTM encode, round 6: persistent cooperative kernel, fixed barrier.
// 256 blocks (1/CU) x 512 threads (8 waves). K=672 split across 8 waves.
// Per-step sync = 8 independent 32-block barriers: monotonic counter+flag on
// separate cachelines, RELAXED polling with s_sleep backoff, ONE release fence
// at arrive and ONE acquire fence per wave after the wait. All step-reused
// weights are fence-immune: Bhi in LDS (84 KB), Blo in registers (<=12 bf16x8
// per wave), bias+c in registers. x-tiles computed BEFORE the flag wait.

#define HIDDEN 512
#define TSTEPS 512
#define BATCH 256
#define FEATD 128
#define ACTD 32
#define DIMD 160
#define GATES 2048
#define NKT 21
#define NGROUPS 32
#define NFRAGS (NGROUPS * NKT * 4)   // 2688

#define NWAVES 8
#define SB 66                 // zbuf stride per b-row (f32): 2-way banks on store
#define SW (32 * SB)          // 2112 f32 per wave

typedef short bf16x8 __attribute__((ext_vector_type(8)));
typedef float f32x4 __attribute__((ext_vector_type(4)));

__device__ __forceinline__ unsigned short f2bf(float v) {
    union { float f; unsigned u; } c; c.f = v;
    unsigned r = c.u + 0x7fffu + ((c.u >> 16) & 1u);   // RNE
    return (unsigned short)(r >> 16);
}
__device__ __forceinline__ float bf2f(unsigned short s) {
    union { unsigned u; float f; } c; c.u = ((unsigned)s) << 16; return c.f;
}
__device__ __forceinline__ float fast_sigmoid(float x) {
    return 1.0f / (1.0f + __expf(-x));
}
__device__ __forceinline__ float fast_tanh(float x) {
    return 1.0f - 2.0f / (__expf(2.0f * x) + 1.0f);
}

// ---- pack [W;U] (672 x 2048 fp32) into B-fragment-ordered hi/lo bf16 -------
// frag f = (ng*NKT + kt)*4 + tc; element (lane,j) = B[k][col],
// k = kt*32 + (lane>>4)*8 + j, col = tc*512 + ng*16 + (lane&15).
__global__ __launch_bounds__(256)
void pack_weights(const float* __restrict__ W, const float* __restrict__ U,
                  unsigned short* __restrict__ Bhi, unsigned short* __restrict__ Blo)
{
    const int idx = blockIdx.x * 256 + threadIdx.x;
    if (idx >= NFRAGS * 64) return;
    const int lane = idx & 63;
    const int f = idx >> 6;
    const int tc = f & 3;
    const int kt = (f >> 2) % NKT;
    const int ng = (f >> 2) / NKT;
    const int col = tc * HIDDEN + ng * 16 + (lane & 15);
    const int kbase = kt * 32 + (lane >> 4) * 8;
    #pragma unroll
    for (int j = 0; j < 8; ++j) {
        const int k = kbase + j;
        const float v = (k < DIMD) ? W[(size_t)k * GATES + col]
                                   : U[(size_t)(k - DIMD) * GATES + col];
        const unsigned short hi = f2bf(v);
        Bhi[(size_t)idx * 8 + j] = hi;
        Blo[(size_t)idx * 8 + j] = f2bf(v - bf2f(hi));
    }
}

__device__ __forceinline__ void h_tile(int kt, const bf16x8* blo,
                                       const unsigned short* __restrict__ hin_hi,
                                       const unsigned short* __restrict__ hin_lo,
                                       const unsigned short* lds_bhi,
                                       int m0, int nn, int kg, int lane,
                                       f32x4 (&acc)[2][4])
{
    const int hk = kt * 32 - DIMD + kg * 8;
    bf16x8 ahi[2], alo[2];
    #pragma unroll
    for (int mg = 0; mg < 2; ++mg) {
        const int b = m0 + mg * 16 + nn;
        ahi[mg] = *(const bf16x8*)(hin_hi + (size_t)b * HIDDEN + hk);
        alo[mg] = *(const bf16x8*)(hin_lo + (size_t)b * HIDDEN + hk);
    }
    #pragma unroll
    for (int tc = 0; tc < 4; ++tc) {
        const bf16x8 bhv = *(const bf16x8*)(lds_bhi + (kt * 4 + tc) * 512 + lane * 8);
        #pragma unroll
        for (int mg = 0; mg < 2; ++mg) {
            acc[mg][tc] = __builtin_amdgcn_mfma_f32_16x16x32_bf16(ahi[mg], bhv, acc[mg][tc], 0, 0, 0);
            acc[mg][tc] = __builtin_amdgcn_mfma_f32_16x16x32_bf16(alo[mg], bhv, acc[mg][tc], 0, 0, 0);
            acc[mg][tc] = __builtin_amdgcn_mfma_f32_16x16x32_bf16(ahi[mg], blo[tc], acc[mg][tc], 0, 0, 0);
        }
    }
}

__global__ __launch_bounds__(512, 1)
void lstm_persistent(const float* __restrict__ feat, const float* __restrict__ act,
                     const unsigned short* __restrict__ Bhi,
                     const unsigned short* __restrict__ Blo,
                     const float* __restrict__ bias,
                     unsigned short* __restrict__ h_hi0,
                     unsigned short* __restrict__ h_lo0,
                     unsigned short* __restrict__ h_hi1,
                     unsigned short* __restrict__ h_lo1,
                     float* __restrict__ out,
                     int* __restrict__ bar)
{
    __shared__ unsigned short lds_bhi[84 * 512];   // 86016 B
    __shared__ float zbuf[NWAVES * SW];            // 67584 B  (total 150 KB)

    const int tid = threadIdx.x;
    const int lane = tid & 63;
    const int w = tid >> 6;
    const int ng = blockIdx.x;        // flat%8 = ng%8 -> all mb of one ng on one XCD
    const int mb = blockIdx.y;
    const int m0 = mb * 32;
    const int u0 = ng * 16;
    const int kg = lane >> 4;
    const int nn = lane & 15;

    // ---- stage my Bhi slab (86016 B) into LDS ------------------------------
    {
        const uint4* src = (const uint4*)(Bhi + (size_t)ng * 84 * 512);
        uint4* dst = (uint4*)lds_bhi;
        for (int i = tid; i < 84 * 512 / 8; i += 512) dst[i] = src[i];
    }

    // ---- per-wave K assignment; Blo slices -> registers (fence-immune) -----
    const int ktA = (w < 5) ? w : -1;   // x tile (feat kt<4, act kt==4)
    const int ktB = 5 + 2 * w;          // h tiles: {5,6}..{19,20}
    const int ktC = 6 + 2 * w;
    bf16x8 bloA[4], bloB[4], bloC[4];
    {
        const unsigned short* base = Blo + (size_t)ng * NKT * 2048 + (size_t)lane * 8;
        const int kA = (ktA >= 0) ? ktA : ktB;
        #pragma unroll
        for (int tc = 0; tc < 4; ++tc) {
            bloA[tc] = *(const bf16x8*)(base + (kA  * 4 + tc) * 512);
            bloB[tc] = *(const bf16x8*)(base + (ktB * 4 + tc) * 512);
            bloC[tc] = *(const bf16x8*)(base + (ktC * 4 + tc) * 512);
        }
    }

    // ---- epilogue-role constants: one (row, unit) cell per thread ----------
    const int erow = tid >> 4;          // 0..31
    const int eun = tid & 15;           // 0..15
    float br[4];
    #pragma unroll
    for (int g = 0; g < 4; ++g) br[g] = bias[g * HIDDEN + u0 + eun];
    float c = 0.f;
    const size_t oidx = (size_t)(m0 + erow) * HIDDEN + u0 + eun;

    int* const cnt_p  = bar + mb * 64;        // separate cachelines
    int* const flag_p = bar + mb * 64 + 32;

    __syncthreads();   // LDS Bhi ready

    for (int t = 0; t < TSTEPS; ++t) {
        const unsigned short* hin_hi = (t & 1) ? h_hi1 : h_hi0;
        const unsigned short* hin_lo = (t & 1) ? h_lo1 : h_lo0;
        unsigned short* hout_hi = (t & 1) ? h_hi0 : h_hi1;
        unsigned short* hout_lo = (t & 1) ? h_lo0 : h_lo1;

        f32x4 acc[2][4];
        #pragma unroll
        for (int mg = 0; mg < 2; ++mg)
            #pragma unroll
            for (int tc = 0; tc < 4; ++tc)
                acc[mg][tc] = (f32x4){0.f, 0.f, 0.f, 0.f};

        // ---- x tile (independent of h) BEFORE the wait ---------------------
        if (w < 5) {
            bf16x8 ahi[2], alo[2];
            #pragma unroll
            for (int mg = 0; mg < 2; ++mg) {
                const int b = m0 + mg * 16 + nn;
                const float* src = (ktA < 4)
                    ? feat + ((size_t)b * TSTEPS + t) * FEATD + ktA * 32 + kg * 8
                    : act  + ((size_t)b * TSTEPS + t) * ACTD  + kg * 8;
                const float4 v0 = *(const float4*)src;
                const float4 v1 = *(const float4*)(src + 4);
                const float vv[8] = {v0.x, v0.y, v0.z, v0.w, v1.x, v1.y, v1.z, v1.w};
                #pragma unroll
                for (int j = 0; j < 8; ++j) {
                    const unsigned short h = f2bf(vv[j]);
                    ahi[mg][j] = (short)h;
                    alo[mg][j] = (short)f2bf(vv[j] - bf2f(h));
                }
            }
            #pragma unroll
            for (int tc = 0; tc < 4; ++tc) {
                const bf16x8 bhv = *(const bf16x8*)(lds_bhi + (ktA * 4 + tc) * 512 + lane * 8);
                #pragma unroll
                for (int mg = 0; mg < 2; ++mg) {
                    acc[mg][tc] = __builtin_amdgcn_mfma_f32_16x16x32_bf16(ahi[mg], bhv, acc[mg][tc], 0, 0, 0);
                    acc[mg][tc] = __builtin_amdgcn_mfma_f32_16x16x32_bf16(alo[mg], bhv, acc[mg][tc], 0, 0, 0);
                    acc[mg][tc] = __builtin_amdgcn_mfma_f32_16x16x32_bf16(ahi[mg], bloA[tc], acc[mg][tc], 0, 0, 0);
                }
            }
        }

        // ---- wait for h(t): relaxed poll + one acquire fence per wave ------
        if (lane == 0) {
            while (__hip_atomic_load(flag_p, __ATOMIC_RELAXED,
                                     __HIP_MEMORY_SCOPE_AGENT) < t)
                __builtin_amdgcn_s_sleep(2);
        }
        __threadfence();

        // ---- h tiles --------------------------------------------------------
        h_tile(ktB, bloB, hin_hi, hin_lo, lds_bhi, m0, nn, kg, lane, acc);
        h_tile(ktC, bloC, hin_hi, hin_lo, lds_bhi, m0, nn, kg, lane, acc);

        // ---- partials -> LDS ------------------------------------------------
        #pragma unroll
        for (int mg = 0; mg < 2; ++mg)
            #pragma unroll
            for (int tc = 0; tc < 4; ++tc)
                #pragma unroll
                for (int r = 0; r < 4; ++r)
                    zbuf[w * SW + (mg * 16 + kg * 4 + r) * SB + tc * 16 + nn] = acc[mg][tc][r];
        __syncthreads();

        // ---- reduce + gates; c in regs --------------------------------------
        float zg[4];
        #pragma unroll
        for (int g = 0; g < 4; ++g) {
            float s = 0.f;
            #pragma unroll
            for (int ww = 0; ww < NWAVES; ++ww)
                s += zbuf[ww * SW + erow * SB + g * 16 + eun];
            zg[g] = s;
        }
        const float ig = fast_sigmoid(zg[0] + br[0]);
        const float fg = fast_sigmoid(zg[1] + br[1]);
        const float gg = fast_tanh   (zg[2] + br[2]);
        const float og = fast_sigmoid(zg[3] + br[3]);
        c = fg * c + ig * gg;
        const float hv = og * fast_tanh(c);
        const unsigned short hh = f2bf(hv);
        hout_hi[oidx] = hh;
        hout_lo[oidx] = f2bf(hv - bf2f(hh));
        if (t == TSTEPS - 1) out[oidx] = hv;

        // ---- arrive: one release fence + relaxed add; last sets flag --------
        __syncthreads();                 // all h-stores of the block issued
        if (tid == 0) {
            __threadfence();             // release h-writes to agent scope
            const int old = __hip_atomic_fetch_add(cnt_p, 1, __ATOMIC_RELAXED,
                                                   __HIP_MEMORY_SCOPE_AGENT);
            if (old == NGROUPS * (t + 1) - 1)
                __hip_atomic_store(flag_p, t + 1, __ATOMIC_RELEASE,
                                   __HIP_MEMORY_SCOPE_AGENT);
        }
    }
}

extern "C" void kernel_launch(void* const* d_in, const int* in_sizes, int n_in,
                              void* d_out, int out_size, void* d_ws, size_t ws_size,
                              hipStream_t stream) {
    const float* features = (const float*)d_in[0];
    const float* actions  = (const float*)d_in[1];
    const float* W        = (const float*)d_in[2];
    const float* U        = (const float*)d_in[3];
    const float* bias     = (const float*)d_in[4];
    float* out = (float*)d_out;

    const size_t HB = (size_t)BATCH * HIDDEN;          // 131072 elems
    unsigned short* h_hi0 = (unsigned short*)d_ws;
    unsigned short* h_lo0 = h_hi0 + HB;
    unsigned short* h_hi1 = h_lo0 + HB;
    unsigned short* h_lo1 = h_hi1 + HB;
    int* bar = (int*)(h_lo1 + HB);                     // 8 groups x 64 ints (2 KB)
    unsigned short* Bhi = (unsigned short*)((char*)bar + 2048);
    unsigned short* Blo = Bhi + (size_t)NFRAGS * 512;

    // zero h ping/pong (hi/lo, 4 x 256 KB) + barrier state (2 KB)
    hipMemsetAsync(d_ws, 0, HB * 2 * 4 + 2048, stream);
    pack_weights<<<(NFRAGS * 64 + 255) / 256, 256, 0, stream>>>(W, U, Bhi, Blo);

    void* args[] = { (void*)&features, (void*)&actions, (void*)&Bhi, (void*)&Blo,
                     (void*)&bias, (void*)&h_hi0, (void*)&h_lo0, (void*)&h_hi1,
                     (void*)&h_lo1, (void*)&out, (void*)&bar };
    hipLaunchCooperativeKernel((const void*)lstm_persistent,
                               dim3(NGROUPS, BATCH / 32), dim3(512),
                               args, 0, stream);
}

// Round 7
// 4271.817 us; speedup vs baseline: 5.6361x; 5.6361x over previous
//
#include <hip/hip_runtime.h>
#include <math.h>

// LSTM encode, round 7: back to 512-launch graph (kernel boundary = free
// device-wide release/acquire, ~2us gap) with the round-6 exec upgrades:
// 8 waves/block (2/SIMD), K=672 split 8 ways, batched register loads,
// bf16x3 split MFMA, LDS zbuf reduce, 1-cell-per-thread epilogue.

#define HIDDEN 512
#define TSTEPS 512
#define BATCH 256
#define FEATD 128
#define ACTD 32
#define DIMD 160
#define GATES 2048
#define NKT 21
#define NGROUPS 32
#define NFRAGS (NGROUPS * NKT * 4)   // 2688

#define NWAVES 8
#define SB 66                 // zbuf stride per b-row (f32): 2-way banks (free)
#define SW (32 * SB)

typedef short bf16x8 __attribute__((ext_vector_type(8)));
typedef float f32x4 __attribute__((ext_vector_type(4)));

__device__ __forceinline__ unsigned short f2bf(float v) {
    union { float f; unsigned u; } c; c.f = v;
    unsigned r = c.u + 0x7fffu + ((c.u >> 16) & 1u);   // RNE
    return (unsigned short)(r >> 16);
}
__device__ __forceinline__ float bf2f(unsigned short s) {
    union { unsigned u; float f; } c; c.u = ((unsigned)s) << 16; return c.f;
}
__device__ __forceinline__ float fast_sigmoid(float x) {
    return 1.0f / (1.0f + __expf(-x));
}
__device__ __forceinline__ float fast_tanh(float x) {
    return 1.0f - 2.0f / (__expf(2.0f * x) + 1.0f);
}

// ---- pack [W;U] (672 x 2048 fp32) into B-fragment-ordered hi/lo bf16 -------
// frag f = (ng*NKT + kt)*4 + tc; element (lane,j) = B[k][col],
// k = kt*32 + (lane>>4)*8 + j, col = tc*512 + ng*16 + (lane&15).
__global__ __launch_bounds__(256)
void pack_weights(const float* __restrict__ W, const float* __restrict__ U,
                  unsigned short* __restrict__ Bhi, unsigned short* __restrict__ Blo)
{
    const int idx = blockIdx.x * 256 + threadIdx.x;
    if (idx >= NFRAGS * 64) return;
    const int lane = idx & 63;
    const int f = idx >> 6;
    const int tc = f & 3;
    const int kt = (f >> 2) % NKT;
    const int ng = (f >> 2) / NKT;
    const int col = tc * HIDDEN + ng * 16 + (lane & 15);
    const int kbase = kt * 32 + (lane >> 4) * 8;
    #pragma unroll
    for (int j = 0; j < 8; ++j) {
        const int k = kbase + j;
        const float v = (k < DIMD) ? W[(size_t)k * GATES + col]
                                   : U[(size_t)(k - DIMD) * GATES + col];
        const unsigned short hi = f2bf(v);
        Bhi[(size_t)idx * 8 + j] = hi;
        Blo[(size_t)idx * 8 + j] = f2bf(v - bf2f(hi));
    }
}

__global__ __launch_bounds__(512)
void lstm_step(const float* __restrict__ feat, const float* __restrict__ act,
               const unsigned short* __restrict__ Bhi,
               const unsigned short* __restrict__ Blo,
               const float* __restrict__ bias,
               const unsigned short* __restrict__ hin_hi,
               const unsigned short* __restrict__ hin_lo,
               unsigned short* __restrict__ hout_hi,
               unsigned short* __restrict__ hout_lo,
               float* __restrict__ c_st, float* __restrict__ out,
               int t, int last)
{
    __shared__ float zbuf[NWAVES * SW];          // 67.6 KB

    const int tid = threadIdx.x;
    const int lane = tid & 63;
    const int w = tid >> 6;
    const int ng = blockIdx.x;        // fastest -> XCD holds 4 ng weight slabs
    const int mb = blockIdx.y;
    const int m0 = mb * 32;
    const int u0 = ng * 16;
    const int kg = lane >> 4;
    const int nn = lane & 15;

    const unsigned short* bhbase = Bhi + (size_t)ng * NKT * 2048 + (size_t)lane * 8;
    const unsigned short* blbase = Blo + (size_t)ng * NKT * 2048 + (size_t)lane * 8;

    f32x4 acc[2][4];
    #pragma unroll
    for (int mg = 0; mg < 2; ++mg)
        #pragma unroll
        for (int tc = 0; tc < 4; ++tc)
            acc[mg][tc] = (f32x4){0.f, 0.f, 0.f, 0.f};

    const int ktB = 5 + 2 * w;        // h tiles: {5,6}..{19,20}
    const int ktC = 6 + 2 * w;

    // ---- batch-load ALL fragments for this wave's k-tiles into registers ---
    // h tiles (all 8 waves)
    bf16x8 hB_hi[2], hB_lo[2], hC_hi[2], hC_lo[2];
    bf16x8 bhB[4], blB[4], bhC[4], blC[4];
    {
        const int hkB = ktB * 32 - DIMD + kg * 8;
        const int hkC = ktC * 32 - DIMD + kg * 8;
        #pragma unroll
        for (int mg = 0; mg < 2; ++mg) {
            const int b = m0 + mg * 16 + nn;
            hB_hi[mg] = *(const bf16x8*)(hin_hi + (size_t)b * HIDDEN + hkB);
            hB_lo[mg] = *(const bf16x8*)(hin_lo + (size_t)b * HIDDEN + hkB);
            hC_hi[mg] = *(const bf16x8*)(hin_hi + (size_t)b * HIDDEN + hkC);
            hC_lo[mg] = *(const bf16x8*)(hin_lo + (size_t)b * HIDDEN + hkC);
        }
        #pragma unroll
        for (int tc = 0; tc < 4; ++tc) {
            bhB[tc] = *(const bf16x8*)(bhbase + (ktB * 4 + tc) * 512);
            blB[tc] = *(const bf16x8*)(blbase + (ktB * 4 + tc) * 512);
            bhC[tc] = *(const bf16x8*)(bhbase + (ktC * 4 + tc) * 512);
            blC[tc] = *(const bf16x8*)(blbase + (ktC * 4 + tc) * 512);
        }
    }

    // x tile (waves 0..4 only; wave-uniform branch)
    if (w < 5) {
        const int ktA = w;
        bf16x8 ahi[2], alo[2];
        #pragma unroll
        for (int mg = 0; mg < 2; ++mg) {
            const int b = m0 + mg * 16 + nn;
            const float* src = (ktA < 4)
                ? feat + ((size_t)b * TSTEPS + t) * FEATD + ktA * 32 + kg * 8
                : act  + ((size_t)b * TSTEPS + t) * ACTD  + kg * 8;
            const float4 v0 = *(const float4*)src;
            const float4 v1 = *(const float4*)(src + 4);
            const float vv[8] = {v0.x, v0.y, v0.z, v0.w, v1.x, v1.y, v1.z, v1.w};
            #pragma unroll
            for (int j = 0; j < 8; ++j) {
                const unsigned short h = f2bf(vv[j]);
                ahi[mg][j] = (short)h;
                alo[mg][j] = (short)f2bf(vv[j] - bf2f(h));
            }
        }
        #pragma unroll
        for (int tc = 0; tc < 4; ++tc) {
            const bf16x8 bhv = *(const bf16x8*)(bhbase + (ktA * 4 + tc) * 512);
            const bf16x8 blv = *(const bf16x8*)(blbase + (ktA * 4 + tc) * 512);
            #pragma unroll
            for (int mg = 0; mg < 2; ++mg) {
                acc[mg][tc] = __builtin_amdgcn_mfma_f32_16x16x32_bf16(ahi[mg], bhv, acc[mg][tc], 0, 0, 0);
                acc[mg][tc] = __builtin_amdgcn_mfma_f32_16x16x32_bf16(alo[mg], bhv, acc[mg][tc], 0, 0, 0);
                acc[mg][tc] = __builtin_amdgcn_mfma_f32_16x16x32_bf16(ahi[mg], blv, acc[mg][tc], 0, 0, 0);
            }
        }
    }

    // ---- h-tile MFMA chains -------------------------------------------------
    #pragma unroll
    for (int tc = 0; tc < 4; ++tc) {
        #pragma unroll
        for (int mg = 0; mg < 2; ++mg) {
            acc[mg][tc] = __builtin_amdgcn_mfma_f32_16x16x32_bf16(hB_hi[mg], bhB[tc], acc[mg][tc], 0, 0, 0);
            acc[mg][tc] = __builtin_amdgcn_mfma_f32_16x16x32_bf16(hB_lo[mg], bhB[tc], acc[mg][tc], 0, 0, 0);
            acc[mg][tc] = __builtin_amdgcn_mfma_f32_16x16x32_bf16(hB_hi[mg], blB[tc], acc[mg][tc], 0, 0, 0);
        }
    }
    #pragma unroll
    for (int tc = 0; tc < 4; ++tc) {
        #pragma unroll
        for (int mg = 0; mg < 2; ++mg) {
            acc[mg][tc] = __builtin_amdgcn_mfma_f32_16x16x32_bf16(hC_hi[mg], bhC[tc], acc[mg][tc], 0, 0, 0);
            acc[mg][tc] = __builtin_amdgcn_mfma_f32_16x16x32_bf16(hC_lo[mg], bhC[tc], acc[mg][tc], 0, 0, 0);
            acc[mg][tc] = __builtin_amdgcn_mfma_f32_16x16x32_bf16(hC_hi[mg], blC[tc], acc[mg][tc], 0, 0, 0);
        }
    }

    // ---- partials -> LDS ----------------------------------------------------
    #pragma unroll
    for (int mg = 0; mg < 2; ++mg)
        #pragma unroll
        for (int tc = 0; tc < 4; ++tc)
            #pragma unroll
            for (int r = 0; r < 4; ++r)
                zbuf[w * SW + (mg * 16 + kg * 4 + r) * SB + tc * 16 + nn] = acc[mg][tc][r];
    __syncthreads();

    // ---- reduce + gates: one (row, unit) cell per thread --------------------
    const int erow = tid >> 4;          // 0..31
    const int eun = tid & 15;           // 0..15
    float zg[4];
    #pragma unroll
    for (int g = 0; g < 4; ++g) {
        float s = 0.f;
        #pragma unroll
        for (int ww = 0; ww < NWAVES; ++ww)
            s += zbuf[ww * SW + erow * SB + g * 16 + eun];
        zg[g] = s;
    }
    const float ig = fast_sigmoid(zg[0] + bias[0 * HIDDEN + u0 + eun]);
    const float fg = fast_sigmoid(zg[1] + bias[1 * HIDDEN + u0 + eun]);
    const float gg = fast_tanh   (zg[2] + bias[2 * HIDDEN + u0 + eun]);
    const float og = fast_sigmoid(zg[3] + bias[3 * HIDDEN + u0 + eun]);
    const size_t oidx = (size_t)(m0 + erow) * HIDDEN + u0 + eun;
    const float cn = fg * c_st[oidx] + ig * gg;
    c_st[oidx] = cn;
    const float hv = og * fast_tanh(cn);
    const unsigned short hh = f2bf(hv);
    hout_hi[oidx] = hh;
    hout_lo[oidx] = f2bf(hv - bf2f(hh));
    if (last) out[oidx] = hv;
}

extern "C" void kernel_launch(void* const* d_in, const int* in_sizes, int n_in,
                              void* d_out, int out_size, void* d_ws, size_t ws_size,
                              hipStream_t stream) {
    const float* features = (const float*)d_in[0];
    const float* actions  = (const float*)d_in[1];
    const float* W        = (const float*)d_in[2];
    const float* U        = (const float*)d_in[3];
    const float* bias     = (const float*)d_in[4];
    float* out = (float*)d_out;

    const size_t HB = (size_t)BATCH * HIDDEN;          // 131072 elems
    unsigned short* h_hi0 = (unsigned short*)d_ws;
    unsigned short* h_lo0 = h_hi0 + HB;
    unsigned short* h_hi1 = h_lo0 + HB;
    unsigned short* h_lo1 = h_hi1 + HB;
    float* c_st = (float*)(h_lo1 + HB);
    unsigned short* Bhi = (unsigned short*)(c_st + HB);
    unsigned short* Blo = Bhi + (size_t)NFRAGS * 512;

    // zero h ping/pong (hi/lo) + c: 12 B per (b,u) cell
    hipMemsetAsync(d_ws, 0, HB * 12, stream);
    pack_weights<<<(NFRAGS * 64 + 255) / 256, 256, 0, stream>>>(W, U, Bhi, Blo);

    dim3 grid(NGROUPS, BATCH / 32);                  // 32 x 8 = 256 blocks, 1/CU
    for (int t = 0; t < TSTEPS; ++t) {
        const unsigned short* hih = (t & 1) ? h_hi1 : h_hi0;
        const unsigned short* hil = (t & 1) ? h_lo1 : h_lo0;
        unsigned short* hoh = (t & 1) ? h_hi0 : h_hi1;
        unsigned short* hol = (t & 1) ? h_lo0 : h_lo1;
        lstm_step<<<grid, 512, 0, stream>>>(features, actions, Bhi, Blo, bias,
                                            hih, hil, hoh, hol, c_st, out,
                                            t, t == TSTEPS - 1);
    }
}